// Round 14
// baseline (675.369 us; speedup 1.0000x reference)
//
#include <hip/hip_runtime.h>

#define L_DIM 128
#define BB 8          // real batch rows per block (padded to 16 for MFMA)

typedef _Float16 f16;
typedef _Float16 f16x8 __attribute__((ext_vector_type(8)));
typedef float f32x4 __attribute__((ext_vector_type(4)));

// tanh(u + b) with bias pre-scaled into the exp2 argument: bk = 2*log2(e)*b.
__device__ __forceinline__ float fast_tanh_b(float x, float bk) {
    float e = __builtin_amdgcn_exp2f(fmaf(x, 2.8853900817779268f, bk));
    float r = __builtin_amdgcn_rcpf(e + 1.0f);
    return fmaf(-2.0f, r, 1.0f);   // large +x -> 1; large -x -> -1
}

// waves_per_eu(2): unified budget 256 regs/wave (128 arch + 128 AGPR w2f).
__attribute__((amdgpu_flat_work_group_size(512, 512), amdgpu_waves_per_eu(2)))
__global__ void
cde_kernel(const float* __restrict__ coeffs,
           const float* __restrict__ W_init, const float* __restrict__ b_init,
           const float* __restrict__ W1, const float* __restrict__ b1,
           const float* __restrict__ W2, const float* __restrict__ b2,
           const float* __restrict__ W_out, const float* __restrict__ b_out,
           float* __restrict__ out)
{
    __shared__ __align__(16) f16   z16[16][72];        // fp16 z (rows 8-15 = 0, static)
    __shared__ __align__(16) f16   h16[16][136];       // fp16 hidden activations
    __shared__ __align__(16) float dxT[2][3][16][20];  // [buf][which][c][b]
    __shared__ __align__(16) float zf[BB][64];         // epilogue gather

    const int tid  = threadIdx.x;
    const int blk  = blockIdx.x;
    const int lane = tid & 63;
    const int w    = tid >> 6;        // wave 0..7
    const int q    = lane >> 4;       // quarter-wave 0..3
    const int lr   = lane & 15;
    // GEMM2 column permutation: col lr of tile tau -> outc = hh*16 + c with
    //   hh = w*8 + (lr&7)  (lane-invariant over tau),  c = 2*tau + (lr>>3)
    // => c-sum = register accumulate over tau + ONE shfl_xor(8).
    const int hh   = w * 8 + (lr & 7);
    const int chp  = lr >> 3;
    // After lane-compression this lane owns rows row0, row0+1 (all real):
    const int row0 = (q & 1) * 4 + (q >> 1) * 2;   // q: 0->0, 1->4, 2->2, 3->6

    // ---- one-time: weight fragments into registers ----
    f16x8 w2f[8][4];
    float b2k[8];
#pragma unroll
    for (int t8 = 0; t8 < 8; ++t8) {
        const int outc = hh * 16 + 2 * t8 + chp;
        b2k[t8] = 2.8853900817779268f * b2[outc];
#pragma unroll
        for (int kc = 0; kc < 4; ++kc) {
            const float* src = W2 + (size_t)outc * 128 + kc * 32 + q * 8;
            f16x8 v;
#pragma unroll
            for (int i = 0; i < 8; ++i) v[i] = (f16)src[i];
            w2f[t8][kc] = v;
        }
    }
    f16x8 w1f[2];
#pragma unroll
    for (int kc = 0; kc < 2; ++kc) {
        const float* src = W1 + (size_t)(w * 16 + lr) * 64 + kc * 32 + q * 8;
        f16x8 v;
#pragma unroll
        for (int i = 0; i < 8; ++i) v[i] = (f16)src[i];
        w1f[kc] = v;
    }
    const float b1r = b1[w * 16 + lr];
    const f32x4 zero4 = {0.f, 0.f, 0.f, 0.f};   // persistent C-init quad

    // ---- init: z0 = X0 @ W_init^T + b_init for (b = row0+j, hh) ----
    float z32r[2], ksumr[2];
#pragma unroll
    for (int j = 0; j < 2; ++j) {
        const float* x0 = coeffs + (size_t)(blk * BB + row0 + j) * (L_DIM - 1) * 64;
        float a = b_init[hh];
#pragma unroll
        for (int c = 0; c < 16; ++c) a = fmaf(x0[c], W_init[hh * 16 + c], a);
        z32r[j] = a;
        ksumr[j] = 0.f;
        if (lr < 8) z16[row0 + j][hh] = (f16)a;   // lr<8 <=> chp==0; hh=w*8+lr
    }
    for (int i = tid; i < 8 * 72; i += 512) z16[8 + i / 72][i % 72] = (f16)0.f;  // pad rows
    if (tid < BB * 16) {   // spline derivs for step 0 -> buffer 0
        const int b = tid >> 4, c = tid & 15;
        const float* seg = coeffs + (size_t)(blk * BB + b) * (L_DIM - 1) * 64;
        float bv = seg[16 + c], cv = seg[32 + c], dv = seg[48 + c];
        dxT[0][0][c][b] = bv;
        dxT[0][1][c][b] = fmaf(0.25f, dv, fmaf(0.5f, cv, bv));
        dxT[0][2][c][b] = seg[64 + 16 + c];
    }
    __syncthreads();

    // 4-MFMA chain for one tile (C from persistent zero quad)
#define G2T(dst, T) \
    f32x4 dst = __builtin_amdgcn_mfma_f32_16x16x32_f16(af0, w2f[T][0], zero4, 0, 0, 0); \
    dst = __builtin_amdgcn_mfma_f32_16x16x32_f16(af1, w2f[T][1], dst, 0, 0, 0);         \
    dst = __builtin_amdgcn_mfma_f32_16x16x32_f16(af2, w2f[T][2], dst, 0, 0, 0);         \
    dst = __builtin_amdgcn_mfma_f32_16x16x32_f16(af3, w2f[T][3], dst, 0, 0, 0);
    // per-tile dX broadcast load (issued just after the tile's chain)
#define G2DV(T) const float2 dv##T = *(const float2*)&dxT[buf][ds][2 * (T) + chp][row0];
    // tail for one finished tile: compress (rows 0-7 real) -> tanh -> dX-fma
#define G2TAIL(src, T) {                                                  \
    float u0 = __shfl_xor(src[2], 32);                                    \
    float u1 = __shfl_xor(src[3], 32);                                    \
    float g0 = fast_tanh_b((lane < 32) ? src[0] : u0, b2k[T]);            \
    float g1 = fast_tanh_b((lane < 32) ? src[1] : u1, b2k[T]);            \
    ka0 = fmaf(g0, dv##T.x, ka0);                                         \
    ka1 = fmaf(g1, dv##T.y, ka1); }

    // ---- main loop: 127 RK4 steps x 4 f-evals, 2 barriers per f-eval ----
    for (int t = 0; t < L_DIM - 1; ++t) {
        const int buf = t & 1;
        float pb = 0.f, pc = 0.f, pd = 0.f, pe = 0.f;   // dxT prefetch (s2 load, s3 write)
#pragma unroll
        for (int s = 0; s < 4; ++s) {
            // Phase A: GEMM1  h = relu(z @ W1^T + b1)
            {
                f16x8 za0 = *(const f16x8*)&z16[lr][q * 8];
                f16x8 za1 = *(const f16x8*)&z16[lr][32 + q * 8];
                f32x4 hacc = __builtin_amdgcn_mfma_f32_16x16x32_f16(za0, w1f[0], zero4, 0, 0, 0);
                hacc = __builtin_amdgcn_mfma_f32_16x16x32_f16(za1, w1f[1], hacc, 0, 0, 0);
#pragma unroll
                for (int r = 0; r < 4; ++r)
                    h16[q * 4 + r][w * 16 + lr] = (f16)fmaxf(hacc[r] + b1r, 0.f);
            }
            __syncthreads();

            // Phase B: GEMM2 as ONE flat 8-tile software pipeline. Every tail
            // (except the last) runs with the next tile's 4-MFMA chain still in
            // flight; af fragments hoisted (loop-invariant across tiles).
            const int ds = (s + 1) >> 1;            // 0,1,1,2
            float ka0 = 0.f, ka1 = 0.f;
            const f16x8 af0 = *(const f16x8*)&h16[lr][q * 8];
            const f16x8 af1 = *(const f16x8*)&h16[lr][32 + q * 8];
            const f16x8 af2 = *(const f16x8*)&h16[lr][64 + q * 8];
            const f16x8 af3 = *(const f16x8*)&h16[lr][96 + q * 8];
            G2T(a0, 0) G2DV(0)
            G2T(a1, 1) G2DV(1)
            G2TAIL(a0, 0)
            G2T(a2, 2) G2DV(2)
            G2TAIL(a1, 1)
            G2T(a3, 3) G2DV(3)
            G2TAIL(a2, 2)
            G2T(a4, 4) G2DV(4)
            if (s == 2 && t < L_DIM - 2 && tid < 128) {   // issue next-step spline loads
                const int b = tid >> 4, c = tid & 15;
                const float* seg = coeffs + ((size_t)(blk * BB + b) * (L_DIM - 1) + (t + 1)) * 64;
                pb = seg[16 + c]; pc = seg[32 + c]; pd = seg[48 + c];
                pe = (t + 1 < L_DIM - 2) ? seg[80 + c] : 0.f;
            }
            G2TAIL(a3, 3)
            G2T(a5, 5) G2DV(5)
            G2TAIL(a4, 4)
            G2T(a6, 6) G2DV(6)
            G2TAIL(a5, 5)
            G2T(a7, 7) G2DV(7)
            G2TAIL(a6, 6)
            G2TAIL(a7, 7)
            // complete the c-sum: one shuffle (partner lane lr^8 has other parity)
            ka0 += __shfl_xor(ka0, 8);
            ka1 += __shfl_xor(ka1, 8);
            // RK4 stage update in registers (uniform scalar branches on s)
            float zs0, zs1;
            if (s == 3) {
                z32r[0] = fmaf(ksumr[0] + ka0, 1.f / 6.f, z32r[0]); zs0 = z32r[0];
                z32r[1] = fmaf(ksumr[1] + ka1, 1.f / 6.f, z32r[1]); zs1 = z32r[1];
            } else {
                ksumr[0] = (s == 0) ? ka0 : fmaf(2.f, ka0, ksumr[0]);
                ksumr[1] = (s == 0) ? ka1 : fmaf(2.f, ka1, ksumr[1]);
                const float alpha = (s == 2) ? 1.f : 0.5f;
                zs0 = fmaf(alpha, ka0, z32r[0]);
                zs1 = fmaf(alpha, ka1, z32r[1]);
            }
            if (lr < 8) {
                z16[row0 + 0][hh] = (f16)zs0;
                z16[row0 + 1][hh] = (f16)zs1;
            }
            if (s == 3 && t < L_DIM - 2 && tid < 128) {   // write next-step spline derivs
                const int b = tid >> 4, c = tid & 15;
                dxT[buf ^ 1][0][c][b] = pb;
                dxT[buf ^ 1][1][c][b] = fmaf(0.25f, pd, fmaf(0.5f, pc, pb));
                dxT[buf ^ 1][2][c][b] = (t + 1 < L_DIM - 2) ? pe : (pb + pc + pd);
            }
            __syncthreads();
        }
    }

    // ---- epilogue: out = zT @ W_out^T + b_out ----
    if (lr < 8) {
        zf[row0 + 0][hh] = z32r[0];
        zf[row0 + 1][hh] = z32r[1];
    }
    __syncthreads();
    if (tid < 64) {
        const int b = lane >> 3, j0 = lane & 7;
        float p = 0.f;
#pragma unroll
        for (int m = 0; m < 8; ++m) p += zf[b][j0 + 8 * m] * W_out[j0 + 8 * m];
        p += __shfl_xor(p, 1, 64);
        p += __shfl_xor(p, 2, 64);
        p += __shfl_xor(p, 4, 64);
        if (j0 == 0) out[blk * BB + b] = p + b_out[0];
    }
}

extern "C" void kernel_launch(void* const* d_in, const int* in_sizes, int n_in,
                              void* d_out, int out_size, void* d_ws, size_t ws_size,
                              hipStream_t stream) {
    const float* coeffs = (const float*)d_in[0];
    const float* W_init = (const float*)d_in[1];
    const float* b_init = (const float*)d_in[2];
    const float* W1     = (const float*)d_in[3];
    const float* b1     = (const float*)d_in[4];
    const float* W2     = (const float*)d_in[5];
    const float* b2     = (const float*)d_in[6];
    const float* W_out  = (const float*)d_in[7];
    const float* b_out  = (const float*)d_in[8];
    cde_kernel<<<256, 512, 0, stream>>>(coeffs, W_init, b_init, W1, b1, W2, b2,
                                        W_out, b_out, (float*)d_out);
}

// Round 15
// 666.500 us; speedup vs baseline: 1.0133x; 1.0133x over previous
//
#include <hip/hip_runtime.h>

#define L_DIM 128
#define BB 8          // real batch rows per block (padded to 16 for MFMA)

typedef _Float16 f16;
typedef _Float16 f16x4 __attribute__((ext_vector_type(4)));
typedef _Float16 f16x8 __attribute__((ext_vector_type(8)));
typedef float f32x4 __attribute__((ext_vector_type(4)));

// tanh(u + b) with bias pre-scaled into the exp2 argument: bk = 2*log2(e)*b.
__device__ __forceinline__ float fast_tanh_b(float x, float bk) {
    float e = __builtin_amdgcn_exp2f(fmaf(x, 2.8853900817779268f, bk));
    float r = __builtin_amdgcn_rcpf(e + 1.0f);
    return fmaf(-2.0f, r, 1.0f);   // large +x -> 1; large -x -> -1
}

// waves_per_eu(2): unified budget 256 regs/wave (128 arch + 128 AGPR w2f).
__attribute__((amdgpu_flat_work_group_size(512, 512), amdgpu_waves_per_eu(2)))
__global__ void
cde_kernel(const float* __restrict__ coeffs,
           const float* __restrict__ W_init, const float* __restrict__ b_init,
           const float* __restrict__ W1, const float* __restrict__ b1,
           const float* __restrict__ W2, const float* __restrict__ b2,
           const float* __restrict__ W_out, const float* __restrict__ b_out,
           float* __restrict__ out)
{
    __shared__ __align__(16) f16   z16[16][72];     // fp16 z (rows 8-15 = 0, static)
    __shared__ __align__(16) f16   h16[16][136];    // fp16 hidden activations
    __shared__ __align__(16) float zf[BB][64];      // epilogue gather
    // Whole-trajectory spline-deriv tables (precomputed once; kills the per-step
    // prefetch registers whose spill was the stuck 37MB WRITE_SIZE).
    // dxb[t] = deriv at integer time t (plane 127 = t=126, fr=1 endpoint);
    // dxm[t] = deriv at t+0.5. Layout [c][b], f32 (bit-identical to r13 math).
    __shared__ __align__(16) float dxb[128][16][8];  // 64KB
    __shared__ __align__(16) float dxm[127][16][8];  // 63.5KB  (total ~136KB < 160)

    const int tid  = threadIdx.x;
    const int blk  = blockIdx.x;
    const int lane = tid & 63;
    const int w    = tid >> 6;        // wave 0..7
    const int q    = lane >> 4;       // quarter-wave 0..3
    const int lr   = lane & 15;
    // GEMM2 column permutation: col lr of tile tau -> outc = hh*16 + c with
    //   hh = w*8 + (lr&7)  (lane-invariant over tau),  c = 2*tau + (lr>>3)
    // => c-sum = register accumulate over tau + ONE shfl_xor(8).
    const int hh   = w * 8 + (lr & 7);
    const int chp  = lr >> 3;
    // After lane-compression this lane owns rows row0, row0+1 (all real):
    const int row0 = (q & 1) * 4 + (q >> 1) * 2;   // q: 0->0, 1->4, 2->2, 3->6

    // ---- one-time: weight fragments into registers ----
    f16x8 w2f[8][4];
    float b2k[8];
#pragma unroll
    for (int t8 = 0; t8 < 8; ++t8) {
        const int outc = hh * 16 + 2 * t8 + chp;
        b2k[t8] = 2.8853900817779268f * b2[outc];
#pragma unroll
        for (int kc = 0; kc < 4; ++kc) {
            const float* src = W2 + (size_t)outc * 128 + kc * 32 + q * 8;
            f16x8 v;
#pragma unroll
            for (int i = 0; i < 8; ++i) v[i] = (f16)src[i];
            w2f[t8][kc] = v;
        }
    }
    f16x8 w1f[2];
#pragma unroll
    for (int kc = 0; kc < 2; ++kc) {
        const float* src = W1 + (size_t)(w * 16 + lr) * 64 + kc * 32 + q * 8;
        f16x8 v;
#pragma unroll
        for (int i = 0; i < 8; ++i) v[i] = (f16)src[i];
        w1f[kc] = v;
    }
    // Swapped-G1 bias quad: lane owns hcols w*16 + q*4 + 0..3
    const float4 b1q = *(const float4*)&b1[w * 16 + q * 4];
    const f32x4 zero4 = {0.f, 0.f, 0.f, 0.f};

    // ---- init: z0 = X0 @ W_init^T + b_init for (b = row0+j, hh) ----
    float z32r[2], ksumr[2];
#pragma unroll
    for (int j = 0; j < 2; ++j) {
        const float* x0 = coeffs + (size_t)(blk * BB + row0 + j) * (L_DIM - 1) * 64;
        float a = b_init[hh];
#pragma unroll
        for (int c = 0; c < 16; ++c) a = fmaf(x0[c], W_init[hh * 16 + c], a);
        z32r[j] = a;
        ksumr[j] = 0.f;
        if (lr < 8) z16[row0 + j][hh] = (f16)a;   // lr<8 <=> chp==0; hh=w*8+lr
    }
    for (int i = tid; i < 8 * 72; i += 512) z16[8 + i / 72][i % 72] = (f16)0.f;  // pad rows

    // ---- prologue: fill the whole dx table (c-fast mapping for coalescing) ----
#pragma unroll 2
    for (int i = tid; i < 127 * 128; i += 512) {
        const int t = i >> 7, j = i & 127;
        const int c = j & 15, b = (j >> 4) & 7;
        const float* seg = coeffs + ((size_t)(blk * BB + b) * (L_DIM - 1) + t) * 64;
        const float bv = seg[16 + c], cv = seg[32 + c], dv = seg[48 + c];
        dxb[t][c][b] = bv;
        dxm[t][c][b] = fmaf(0.25f, dv, fmaf(0.5f, cv, bv));
        if (t == 126) dxb[127][c][b] = bv + cv + dv;   // fr = 1 endpoint
    }
    __syncthreads();

    // 4-MFMA chain for one tile (C from persistent zero quad)
#define G2T(dst, T) \
    f32x4 dst = __builtin_amdgcn_mfma_f32_16x16x32_f16(af0, w2f[T][0], zero4, 0, 0, 0); \
    dst = __builtin_amdgcn_mfma_f32_16x16x32_f16(af1, w2f[T][1], dst, 0, 0, 0);         \
    dst = __builtin_amdgcn_mfma_f32_16x16x32_f16(af2, w2f[T][2], dst, 0, 0, 0);         \
    dst = __builtin_amdgcn_mfma_f32_16x16x32_f16(af3, w2f[T][3], dst, 0, 0, 0);
    // tail for one finished tile: compress (rows 0-7 real) -> tanh -> dX-fma
#define G2TAIL(src, T) {                                                  \
    float u0 = __shfl_xor(src[2], 32);                                    \
    float u1 = __shfl_xor(src[3], 32);                                    \
    float g0 = fast_tanh_b((lane < 32) ? src[0] : u0, b2k[T]);            \
    float g1 = fast_tanh_b((lane < 32) ? src[1] : u1, b2k[T]);            \
    ka0 = fmaf(g0, dvv[(T) & 3].x, ka0);                                  \
    ka1 = fmaf(g1, dvv[(T) & 3].y, ka1); }

    // ---- main loop: 127 RK4 steps x 4 f-evals, 2 barriers per f-eval ----
    for (int t = 0; t < L_DIM - 1; ++t) {
#pragma unroll
        for (int s = 0; s < 4; ++s) {
            // Phase A: GEMM1, swapped operands: D[hcol][batch]. Lane holds 4
            // CONSECUTIVE hcols (w*16+q*4+r) for batch lr -> one b64 write.
            {
                f16x8 za0 = *(const f16x8*)&z16[lr][q * 8];
                f16x8 za1 = *(const f16x8*)&z16[lr][32 + q * 8];
                f32x4 hacc = __builtin_amdgcn_mfma_f32_16x16x32_f16(w1f[0], za0, zero4, 0, 0, 0);
                hacc = __builtin_amdgcn_mfma_f32_16x16x32_f16(w1f[1], za1, hacc, 0, 0, 0);
                f16x4 pp;
                pp[0] = (f16)fmaxf(hacc[0] + b1q.x, 0.f);
                pp[1] = (f16)fmaxf(hacc[1] + b1q.y, 0.f);
                pp[2] = (f16)fmaxf(hacc[2] + b1q.z, 0.f);
                pp[3] = (f16)fmaxf(hacc[3] + b1q.w, 0.f);
                *(f16x4*)&h16[lr][w * 16 + q * 4] = pp;
            }
            __syncthreads();

            // Phase B: GEMM2, r13's proven 2-pass tile-interleave (tails overlap
            // the next tile's in-flight MFMA chain). dX from precomputed planes.
            const float* dxp = (s == 0) ? &dxb[t][0][0]
                             : (s == 3) ? &dxb[t + 1][0][0]
                                        : &dxm[t][0][0];
            float ka0 = 0.f, ka1 = 0.f;
#pragma unroll
            for (int hf = 0; hf < 2; ++hf) {
                float2 dvv[4];
#pragma unroll
                for (int tt = 0; tt < 4; ++tt)
                    dvv[tt] = *(const float2*)&dxp[(2 * (hf * 4 + tt) + chp) * 8 + row0];
                const f16x8 af0 = *(const f16x8*)&h16[lr][q * 8];
                const f16x8 af1 = *(const f16x8*)&h16[lr][32 + q * 8];
                const f16x8 af2 = *(const f16x8*)&h16[lr][64 + q * 8];
                const f16x8 af3 = *(const f16x8*)&h16[lr][96 + q * 8];
                G2T(a0, hf * 4 + 0)
                G2T(a1, hf * 4 + 1)
                G2TAIL(a0, hf * 4 + 0)              // overlaps a1's drain
                G2T(a2, hf * 4 + 2)
                G2TAIL(a1, hf * 4 + 1)              // overlaps a2's drain
                G2T(a3, hf * 4 + 3)
                G2TAIL(a2, hf * 4 + 2)              // overlaps a3's drain
                G2TAIL(a3, hf * 4 + 3)
            }
            // complete the c-sum: one shuffle (partner lane lr^8 has other parity)
            ka0 += __shfl_xor(ka0, 8);
            ka1 += __shfl_xor(ka1, 8);
            // RK4 stage update in registers (uniform scalar branches on s)
            float zs0, zs1;
            if (s == 3) {
                z32r[0] = fmaf(ksumr[0] + ka0, 1.f / 6.f, z32r[0]); zs0 = z32r[0];
                z32r[1] = fmaf(ksumr[1] + ka1, 1.f / 6.f, z32r[1]); zs1 = z32r[1];
            } else {
                ksumr[0] = (s == 0) ? ka0 : fmaf(2.f, ka0, ksumr[0]);
                ksumr[1] = (s == 0) ? ka1 : fmaf(2.f, ka1, ksumr[1]);
                const float alpha = (s == 2) ? 1.f : 0.5f;
                zs0 = fmaf(alpha, ka0, z32r[0]);
                zs1 = fmaf(alpha, ka1, z32r[1]);
            }
            if (lr < 8) {
                z16[row0 + 0][hh] = (f16)zs0;
                z16[row0 + 1][hh] = (f16)zs1;
            }
            __syncthreads();
        }
    }

    // ---- epilogue: out = zT @ W_out^T + b_out ----
    if (lr < 8) {
        zf[row0 + 0][hh] = z32r[0];
        zf[row0 + 1][hh] = z32r[1];
    }
    __syncthreads();
    if (tid < 64) {
        const int b = lane >> 3, j0 = lane & 7;
        float p = 0.f;
#pragma unroll
        for (int m = 0; m < 8; ++m) p += zf[b][j0 + 8 * m] * W_out[j0 + 8 * m];
        p += __shfl_xor(p, 1, 64);
        p += __shfl_xor(p, 2, 64);
        p += __shfl_xor(p, 4, 64);
        if (j0 == 0) out[blk * BB + b] = p + b_out[0];
    }
}

extern "C" void kernel_launch(void* const* d_in, const int* in_sizes, int n_in,
                              void* d_out, int out_size, void* d_ws, size_t ws_size,
                              hipStream_t stream) {
    const float* coeffs = (const float*)d_in[0];
    const float* W_init = (const float*)d_in[1];
    const float* b_init = (const float*)d_in[2];
    const float* W1     = (const float*)d_in[3];
    const float* b1     = (const float*)d_in[4];
    const float* W2     = (const float*)d_in[5];
    const float* b2     = (const float*)d_in[6];
    const float* W_out  = (const float*)d_in[7];
    const float* b_out  = (const float*)d_in[8];
    cde_kernel<<<256, 512, 0, stream>>>(coeffs, W_init, b_init, W1, b1, W2, b2,
                                        W_out, b_out, (float*)d_out);
}